// Round 4
// baseline (296.553 us; speedup 1.0000x reference)
//
#include <hip/hip_runtime.h>

// ---------------- workspace layout (float offsets) ----------------
#define AFF_OFF   0u         // [2][1024 p][1024 q]
#define XC_OFF    2097152u   // [2][1024 p][1024 q]
#define K8_OFF    4194304u   // Ktab8 [81 cls][125 item][8] (pad cols 5..7 = 0)
#define BIAS_OFF  4275328u   // [32 l][3 cd][3 ch][3 cw]
#define PART_OFF  4276224u   // topq partials [2][32][3][1024]
#define INV_OFF   4472832u   // inv norms [2 which][2 b][1024]
#define ZP_OFF    4476928u   // zero page (1024 floats)
// total 4477952 floats = 17.9 MB

#define SLOT 2184            // slot stride in floats; 2184 % 32 == 8 (bank-conflict-free)

static __device__ __forceinline__ int imax(int a, int b){ return a > b ? a : b; }
static __device__ __forceinline__ int imin(int a, int b){ return a < b ? a : b; }

static __device__ __forceinline__ void ins3(float& a0, float& a1, float& a2, float v){
  if (v > a0){ a2 = a1; a1 = a0; a0 = v; }
  else if (v > a1){ a2 = a1; a1 = v; }
  else if (v > a2){ a2 = v; }
}

static __device__ __forceinline__ void fma40(const float4 fa, const float4 fb, const float4 fc,
                                             const float4 kq, const float k4, float* acc){
  acc[0] = fmaf(kq.x, fa.x, acc[0]); acc[0] = fmaf(kq.y, fa.y, acc[0]);
  acc[0] = fmaf(kq.z, fa.z, acc[0]); acc[0] = fmaf(kq.w, fa.w, acc[0]);
  acc[0] = fmaf(k4,  fb.x, acc[0]);
  acc[1] = fmaf(kq.x, fa.y, acc[1]); acc[1] = fmaf(kq.y, fa.z, acc[1]);
  acc[1] = fmaf(kq.z, fa.w, acc[1]); acc[1] = fmaf(kq.w, fb.x, acc[1]);
  acc[1] = fmaf(k4,  fb.y, acc[1]);
  acc[2] = fmaf(kq.x, fa.z, acc[2]); acc[2] = fmaf(kq.y, fa.w, acc[2]);
  acc[2] = fmaf(kq.z, fb.x, acc[2]); acc[2] = fmaf(kq.w, fb.y, acc[2]);
  acc[2] = fmaf(k4,  fb.z, acc[2]);
  acc[3] = fmaf(kq.x, fa.w, acc[3]); acc[3] = fmaf(kq.y, fb.x, acc[3]);
  acc[3] = fmaf(kq.z, fb.y, acc[3]); acc[3] = fmaf(kq.w, fb.z, acc[3]);
  acc[3] = fmaf(k4,  fb.w, acc[3]);
  acc[4] = fmaf(kq.x, fb.x, acc[4]); acc[4] = fmaf(kq.y, fb.y, acc[4]);
  acc[4] = fmaf(kq.z, fb.z, acc[4]); acc[4] = fmaf(kq.w, fb.w, acc[4]);
  acc[4] = fmaf(k4,  fc.x, acc[4]);
  acc[5] = fmaf(kq.x, fb.y, acc[5]); acc[5] = fmaf(kq.y, fb.z, acc[5]);
  acc[5] = fmaf(kq.z, fb.w, acc[5]); acc[5] = fmaf(kq.w, fc.x, acc[5]);
  acc[5] = fmaf(k4,  fc.y, acc[5]);
  acc[6] = fmaf(kq.x, fb.z, acc[6]); acc[6] = fmaf(kq.y, fb.w, acc[6]);
  acc[6] = fmaf(kq.z, fc.x, acc[6]); acc[6] = fmaf(kq.w, fc.y, acc[6]);
  acc[6] = fmaf(k4,  fc.z, acc[6]);
  acc[7] = fmaf(kq.x, fb.w, acc[7]); acc[7] = fmaf(kq.y, fc.x, acc[7]);
  acc[7] = fmaf(kq.z, fc.y, acc[7]); acc[7] = fmaf(kq.w, fc.z, acc[7]);
  acc[7] = fmaf(k4,  fc.w, acc[7]);
}

#define GLL4(gsrc, ldst) __builtin_amdgcn_global_load_lds( \
    (const __attribute__((address_space(1))) void*)(gsrc), \
    (__attribute__((address_space(3))) void*)(ldst), 4, 0, 0)

// ---------------- norms only: inv[which][b][p] = 1/max(||x[:,p]||,1e-12) ----------------
__global__ __launch_bounds__(256) void norm_k(const float* __restrict__ xp,
                                              const float* __restrict__ xq,
                                              float* __restrict__ ws){
  int bid = blockIdx.x;                 // 256: which(2) x b(2) x pg(64)
  int pg = bid & 63, b = (bid >> 6) & 1, which = bid >> 7;
  const float* src = (which ? xq : xp) + (size_t)b * 262144;
  int t = threadIdx.x, col = t & 15, cg = t >> 4;
  int p = pg * 16 + col;
  float s = 0.f;
  #pragma unroll
  for (int i = 0; i < 16; ++i){
    float v = src[(size_t)(cg * 16 + i) * 1024 + p];
    s = fmaf(v, v, s);
  }
  __shared__ float red[16][17];
  red[cg][col] = s;
  __syncthreads();
  if (t < 16){
    float tot = 0.f;
    #pragma unroll
    for (int g = 0; g < 16; ++g) tot += red[g][t];
    ws[INV_OFF + (size_t)(which * 2 + b) * 1024 + pg * 16 + t] =
        1.0f / fmaxf(sqrtf(tot), 1e-12f);
  }
}

// ---------------- precompute composed class kernels (padded), bias, zero page ----------------
__global__ __launch_bounds__(256) void tab_k(const float* __restrict__ W1,
                                             const float* __restrict__ B1,
                                             const float* __restrict__ W2,
                                             const float* __restrict__ B2,
                                             float* __restrict__ ws){
  __shared__ float sW1[1296], sW2[1296];
  for (int i = threadIdx.x; i < 1296; i += 256){ sW1[i] = W1[i]; sW2[i] = W2[i]; }
  __syncthreads();
  int tid = blockIdx.x * 256 + threadIdx.x;
  if (tid < 50625){
    int c = tid / 625, r = tid % 625;
    int cw = c % 3, ch = (c / 3) % 3, cd = (c / 9) % 3, cl = c / 27;
    int rw = r % 5, rh = (r / 5) % 5, rd = (r / 25) % 5, rl = r / 125;
    int al0 = imax(0, rl - 2), al1 = imin(2, rl);
    if (cl == 0) al0 = imax(al0, 1);
    if (cl == 2) al1 = imin(al1, 1);
    int ad0 = imax(0, rd - 2), ad1 = imin(2, rd);
    if (cd == 0) ad0 = imax(ad0, 1);
    if (cd == 2) ad1 = imin(ad1, 1);
    int ah0 = imax(0, rh - 2), ah1 = imin(2, rh);
    if (ch == 0) ah0 = imax(ah0, 1);
    if (ch == 2) ah1 = imin(ah1, 1);
    int aw0 = imax(0, rw - 2), aw1 = imin(2, rw);
    if (cw == 0) aw0 = imax(aw0, 1);
    if (cw == 2) aw1 = imin(aw1, 1);
    float s = 0.f;
    for (int a = al0; a <= al1; ++a)
      for (int bq = ad0; bq <= ad1; ++bq)
        for (int cq = ah0; cq <= ah1; ++cq)
          for (int dq = aw0; dq <= aw1; ++dq){
            int q2 = ((a * 3 + bq) * 3 + cq) * 3 + dq;
            int q1 = (((rl - a) * 3 + (rd - bq)) * 3 + (rh - cq)) * 3 + (rw - dq);
            for (int co = 0; co < 16; ++co)
              s += sW2[co * 81 + q2] * sW1[co * 81 + q1];
          }
    int item = (r * 205) >> 10;           // r/5
    int j = r - item * 5;
    ws[K8_OFF + (size_t)c * 1000 + item * 8 + j] = s;
  } else if (tid < 51489){
    int t2 = tid - 50625;
    int l = t2 / 27, rest = t2 % 27;
    int cd = rest / 9, ch = (rest / 3) % 3, cw = rest % 3;
    float v = 0.f;
    for (int i = 0; i < 3; ++i){ int y = l + i - 1; if (y >= 0 && y < 32) v += B2[i]; }
    int jlo = (cd == 0) ? 1 : 0, jhi = (cd == 2) ? 1 : 2;
    int klo = (ch == 0) ? 1 : 0, khi = (ch == 2) ? 1 : 2;
    int mlo = (cw == 0) ? 1 : 0, mhi = (cw == 2) ? 1 : 2;
    for (int i = 0; i < 3; ++i){
      int y = l + i - 1; if (y < 0 || y >= 32) continue;
      for (int co = 0; co < 16; ++co){
        float b1e = 0.f;
        for (int i2 = 0; i2 < 3; ++i2){
          int y2 = y + i2 - 1; if (y2 >= 0 && y2 < 32) b1e += B1[i2 * 16 + co];
        }
        float S = 0.f;
        for (int j = jlo; j <= jhi; ++j)
          for (int k = klo; k <= khi; ++k)
            for (int m = mlo; m <= mhi; ++m)
              S += sW2[co * 81 + ((i * 3 + j) * 3 + k) * 3 + m];
        v += b1e * S;
      }
    }
    ws[BIAS_OFF + t2] = v;
  } else if (tid < 52513){
    ws[ZP_OFF + (tid - 51489)] = 0.f;                 // zero page
  } else if (tid < 82888){
    int u = tid - 52513;                              // pad cols 5..7 of Ktab8
    int c = u / 375, r2 = u % 375;
    int item = r2 / 3, j = 5 + r2 % 3;
    ws[K8_OFF + (size_t)c * 1000 + item * 8 + j] = 0.f;
  }
}

// ---------------- aff = (xp^T xq) scaled by inv norms; 32x64 tiles, K=256 ----------------
__global__ __launch_bounds__(256) void gemm_k(const float* __restrict__ xp,
                                              const float* __restrict__ xq,
                                              float* __restrict__ ws){
  int bid0 = blockIdx.x;
  int bid = (bid0 & 7) * 128 + (bid0 >> 3);   // XCD swizzle (1024 % 8 == 0)
  int qi = bid & 15, pi = (bid >> 4) & 31, b = bid >> 9;
  const float* A = xp + (size_t)b * 262144;   // [c][p]
  const float* B = xq + (size_t)b * 262144;   // [c][q]
  float* C = ws + AFF_OFF + (size_t)b * 1048576;
  const float* invp = ws + INV_OFF + (size_t)b * 1024;
  const float* invq = ws + INV_OFF + 2048u + (size_t)b * 1024;
  int t = threadIdx.x, tx = t & 15, ty = t >> 4;   // ty 0..15 -> 2 p rows each
  int ak = t >> 5, ap = t & 31;
  int bk = t >> 6, bq = t & 63;
  __shared__ float As[16][32], Bs[16][64];
  float acc[2][4] = {};
  for (int k0 = 0; k0 < 256; k0 += 16){
    __syncthreads();
    As[ak][ap]     = A[(size_t)(k0 + ak) * 1024 + pi * 32 + ap];
    As[ak + 8][ap] = A[(size_t)(k0 + ak + 8) * 1024 + pi * 32 + ap];
    #pragma unroll
    for (int r = 0; r < 4; ++r)
      Bs[bk + r * 4][bq] = B[(size_t)(k0 + bk + r * 4) * 1024 + qi * 64 + bq];
    __syncthreads();
    #pragma unroll
    for (int kk = 0; kk < 16; ++kk){
      float2 av = *(const float2*)&As[kk][ty * 2];
      float4 bv = *(const float4*)&Bs[kk][tx * 4];
      acc[0][0] = fmaf(av.x, bv.x, acc[0][0]);
      acc[0][1] = fmaf(av.x, bv.y, acc[0][1]);
      acc[0][2] = fmaf(av.x, bv.z, acc[0][2]);
      acc[0][3] = fmaf(av.x, bv.w, acc[0][3]);
      acc[1][0] = fmaf(av.y, bv.x, acc[1][0]);
      acc[1][1] = fmaf(av.y, bv.y, acc[1][1]);
      acc[1][2] = fmaf(av.y, bv.z, acc[1][2]);
      acc[1][3] = fmaf(av.y, bv.w, acc[1][3]);
    }
  }
  float4 ivb = *(const float4*)&invq[qi * 64 + tx * 4];
  #pragma unroll
  for (int i = 0; i < 2; ++i){
    float iva = invp[pi * 32 + ty * 2 + i];
    float4 v = make_float4(acc[i][0] * iva * ivb.x, acc[i][1] * iva * ivb.y,
                           acc[i][2] * iva * ivb.z, acc[i][3] * iva * ivb.w);
    *(float4*)&C[(size_t)(pi * 32 + ty * 2 + i) * 1024 + qi * 64 + tx * 4] = v;
  }
}

// ---------------- composed 5^4 conv, d-streamed, two-phase overlap ----------------
__global__ __launch_bounds__(256, 3) void conv_k(float* __restrict__ ws){
  __shared__ __align__(16) float lds[5 * SLOT + 2000];   // 12920 f = 51680 B -> 3 blocks/CU
  float* slots = lds;
  float* kvA = lds + 5 * SLOT;

  int bid0 = blockIdx.x;
  int bid = (bid0 & 7) * 128 + (bid0 >> 3);       // XCD swizzle (1024 % 8 == 0)
  int dq = bid & 3, hq = (bid >> 2) & 3, l0 = (bid >> 4) & 31, b = bid >> 9;
  int h0 = hq * 8, dstart = dq * 8;
  int t = threadIdx.x;
  const float* affB = ws + AFF_OFF + (size_t)b * 1048576;
  float* xc = ws + XC_OFF + (size_t)b * 1048576;
  const float* K8G = ws + K8_OFF;
  const float* bias = ws + BIAS_OFF;
  const float* zp = ws + ZP_OFF;

  int cl = (l0 == 0) ? 0 : (l0 == 31) ? 2 : 1;
  int chB = (hq == 0) ? 0 : (hq == 3) ? 2 : 1;    // boundary-row h class (if any)

  // A-phase lane constants: lane = slice(3b) | hsel(1b) | oct(2b)
  int wv = t >> 6, u3 = t & 7;
  int oct = u3 & 3, hl = wv * 2 + (u3 >> 2);      // output row within strip, 0..7
  int hA = h0 + hl;
  int chA = (hA == 0) ? 0 : (hA == 31) ? 2 : 1;
  const float* kvb = ((hq == 0 && hl == 0) || (hq == 3 && hl == 7)) ? kvA : (kvA + 1000);
  int sl = (t >> 3) & 7;
  int dl0s = (sl >= 5) ? 1 : 0;                   // phase start digits
  int dh0s = sl - 5 * dl0s;

  // B-phase lane constants: 16 outputs (8 h x w in {0,31}) x 16 sub-lanes
  int outB = t >> 4, subB = t & 15;
  int hlB = outB >> 1, wx31 = outB & 1;
  int hB = h0 + hlB;
  int chB2 = (hB == 0) ? 0 : (hB == 31) ? 2 : 1;
  int cwB = wx31 ? 2 : 0;
  int wofB = wx31 ? 28 : 0;

  // staging offsets (9 rounds of 256 lanes covering 2160 floats/plane)
  int o0, o1, o2, o3, o4, o5, o6, o7, o8;
#define PRE(r) { int flat = (r)*256 + t; \
    int wi = flat % 36; int rest = flat / 36; int hi = rest % 12; int dl2 = rest / 12; \
    int lp_ = l0 + dl2 - 2, hp_ = h0 + hi - 2, wp_ = wi - 2; \
    bool ok = ((unsigned)lp_ < 32u) && ((unsigned)hp_ < 32u) && ((unsigned)wp_ < 32u); \
    o##r = ok ? (lp_ * 32768 + hp_ * 32 + wp_) : -1; }
  PRE(0) PRE(1) PRE(2) PRE(3) PRE(4) PRE(5) PRE(6) PRE(7) PRE(8)
#undef PRE

#define STG(r, sp_) { const float* s_ = (pOK_ && o##r >= 0) ? (affB + o##r + dpo_) : zp; \
    GLL4(s_, sp_ + (r)*256 + t); }
#define STAGE(si_, dpv_) do { \
    int dp_ = (dpv_); bool pOK_ = ((unsigned)dp_ < 32u); int dpo_ = dp_ * 1024; \
    float* sp_ = slots + (si_) * SLOT; \
    STG(0, sp_) STG(1, sp_) STG(2, sp_) STG(3, sp_) \
    STG(4, sp_) STG(5, sp_) STG(6, sp_) STG(7, sp_) \
    if (t < 112) sp_[2048 + t] = (pOK_ && o8 >= 0) ? affB[o8 + dpo_] : 0.f; \
  } while (0)

#define LKV(r, k0_, k1_) { int ii_ = (r)*256 + t; \
    const float* s_ = (ii_ < 1000) ? (k0_ + ii_) : (k1_ + (ii_ - 1000)); \
    GLL4(s_, kvA + ii_); }
#define LOADKV(cdv_) do { int cd_ = (cdv_); \
    const float* k0_ = K8G + (size_t)((((cl*3+cd_)*3+chB)*3)+1) * 1000; \
    const float* k1_ = K8G + (size_t)((((cl*3+cd_)*3+1)*3)+1) * 1000; \
    LKV(0,k0_,k1_) LKV(1,k0_,k1_) LKV(2,k0_,k1_) LKV(3,k0_,k1_) \
    LKV(4,k0_,k1_) LKV(5,k0_,k1_) LKV(6,k0_,k1_) \
    if (t < 208) kvA[1792 + t] = k1_[792 + t]; \
  } while (0)

#define MITEM(addr_, kvo_) { \
    const float* rp = slots + (addr_); \
    float4 fa = *(const float4*)rp; \
    float4 fb = *(const float4*)(rp + 4); \
    float4 fc = *(const float4*)(rp + 8); \
    const float* kp = kvb + (kvo_) * 8; \
    float4 kq = *(const float4*)kp; \
    float k4 = kp[4]; \
    fma40(fa, fb, fc, kq, k4, acc); }

#define BITEM(addr_, kvix_) { \
    const float4* rp4 = (const float4*)(slots + (addr_)); \
    float4 q1 = rp4[0], q2 = rp4[1]; \
    const float* ka = kgB + (kvix_) * 8; \
    float4 kq = *(const float4*)ka; \
    float k4 = ka[4]; \
    float e0 = wx31 ? q1.w : q1.x; \
    float e1 = wx31 ? q2.x : q1.y; \
    float e2 = wx31 ? q2.y : q1.z; \
    float e3 = wx31 ? q2.z : q1.w; \
    float e4 = wx31 ? q2.w : q2.x; \
    accB = fmaf(kq.x, e0, accB); accB = fmaf(kq.y, e1, accB); \
    accB = fmaf(kq.z, e2, accB); accB = fmaf(kq.w, e3, accB); \
    accB = fmaf(k4,  e4, accB); }

  int cdCur = (dstart == 0) ? 0 : 1;
  LOADKV(cdCur);
  STAGE((dstart + 8)  % 5, dstart - 2);
  STAGE((dstart + 9)  % 5, dstart - 1);
  STAGE((dstart + 10) % 5, dstart);
  STAGE((dstart + 11) % 5, dstart + 1);
  STAGE((dstart + 12) % 5, dstart + 2);
  asm volatile("s_waitcnt vmcnt(0)" ::: "memory");
  __syncthreads();

  for (int s8 = 0; s8 < 8; ++s8){
    int d = dstart + s8;
    int cd = (d == 0) ? 0 : (d == 31) ? 2 : 1;
    if (cd != cdCur){                    // rare: once per block at most
      LOADKV(cd); cdCur = cd;
      asm volatile("s_waitcnt vmcnt(0)" ::: "memory");
      __syncthreads();
    }
    int scomp = (d + 3) % 5;             // slot holding plane d-2 (dd=0)
    const float* kgB = K8G + (size_t)((((cl*3+cd)*3+chB2)*3) + cwB) * 1000;

    float acc[8] = {0.f, 0.f, 0.f, 0.f, 0.f, 0.f, 0.f, 0.f};
    float accB = 0.f;

    // ---- phase 1: dd = 0 items only (reads slot scomp, about to be replaced) ----
    {
      int dl = dl0s, dh = dh0s;
      int addr = scomp * SLOT + (dl * 12 + hl + dh) * 36 + oct * 8;
      int kvo = dl * 25 + dh;
      for (int e = sl; e < 25; e += 8){
        MITEM(addr, kvo)
        dh += 3; dl += 1; addr += 540; kvo += 28;
        if (dh >= 5){ dh -= 5; dl += 1; addr += 252; kvo += 20; }
      }
      for (int e1 = subB; e1 < 25; e1 += 16){
        int dlb = (e1 * 205) >> 10, rhb = e1 - dlb * 5;
        int ab = scomp * SLOT + (dlb * 12 + hlB + rhb) * 36 + wofB;
        BITEM(ab, dlb * 25 + rhb)
      }
    }
    __syncthreads();                     // all reads of slot scomp done
    if (s8 < 7) STAGE(scomp, d + 3);     // async: plane d+3 into slot scomp

    // ---- phase 2: dd = 1..4 items (100), hides staging latency ----
    {
      int dl = dl0s, dh = dh0s;
      int si = scomp + 1; if (si >= 5) si -= 5;
      int addr = si * SLOT + (dl * 12 + hl + dh) * 36 + oct * 8;
      int kvo = dl * 25 + 5 + dh;
      for (int e = sl; e < 100; e += 8){
        MITEM(addr, kvo)
        dh += 3; dl += 1; addr += 540; kvo += 28;
        if (dh >= 5){ dh -= 5; dl += 1; addr += 252; kvo += 20; }
        if (dl >= 5){ dl -= 5; addr += 24; kvo -= 120;
                      si += 1; if (si >= 5){ si -= 5; addr -= 5 * SLOT; } }
      }
      int r = subB, dd = 1;
      for (int e = subB; e < 100; e += 16){
        int dlb = (r * 205) >> 10, rhb = r - dlb * 5;
        int si2 = scomp + dd; if (si2 >= 5) si2 -= 5;
        int ab = si2 * SLOT + (dlb * 12 + hlB + rhb) * 36 + wofB;
        BITEM(ab, dlb * 25 + dd * 5 + rhb)
        r += 16; if (r >= 25){ r -= 25; dd += 1; }
      }
    }

    // ---- reductions + writes ----
    #pragma unroll
    for (int j = 0; j < 8; ++j) acc[j] += __shfl_xor(acc[j], 8);
    #pragma unroll
    for (int j = 0; j < 8; ++j) acc[j] += __shfl_xor(acc[j], 16);
    #pragma unroll
    for (int j = 0; j < 8; ++j) acc[j] += __shfl_xor(acc[j], 32);
    if ((t & 56) == 0){
      float bv = bias[l0 * 27 + cd * 9 + chA * 3 + 1];
      float v[8];
      #pragma unroll
      for (int j = 0; j < 8; ++j) v[j] = acc[j] + bv;
      float* orow = xc + (size_t)(l0 * 32 + d) * 1024 + hA * 32 + oct * 8;
      if (oct == 0){
        orow[1] = v[1];
        *(float2*)&orow[2] = make_float2(v[2], v[3]);
        *(float4*)&orow[4] = make_float4(v[4], v[5], v[6], v[7]);
      } else if (oct == 3){
        *(float4*)&orow[0] = make_float4(v[0], v[1], v[2], v[3]);
        *(float2*)&orow[4] = make_float2(v[4], v[5]);
        orow[6] = v[6];
      } else {
        *(float4*)&orow[0] = make_float4(v[0], v[1], v[2], v[3]);
        *(float4*)&orow[4] = make_float4(v[4], v[5], v[6], v[7]);
      }
    }
    accB += __shfl_xor(accB, 1);
    accB += __shfl_xor(accB, 2);
    accB += __shfl_xor(accB, 4);
    accB += __shfl_xor(accB, 8);
    if (subB == 0){
      float bv = bias[l0 * 27 + cd * 9 + chB2 * 3 + cwB];
      xc[(size_t)(l0 * 32 + d) * 1024 + hB * 32 + (wx31 ? 31 : 0)] = accB + bv;
    }

    asm volatile("s_waitcnt vmcnt(0)" ::: "memory");   // staged plane landed
    __syncthreads();
  }
#undef STG
#undef STAGE
#undef LKV
#undef LOADKV
#undef MITEM
#undef BITEM
}

// ---------------- valp: top3 over q for each (b,p); wave per row, float4 ----------------
__global__ __launch_bounds__(256) void topp_k(const float* __restrict__ ws, float* __restrict__ out){
  const float* xc = ws + XC_OFF;
  int wid = blockIdx.x * 4 + (threadIdx.x >> 6);
  int lane = threadIdx.x & 63;
  int b = wid >> 10, p = wid & 1023;
  const float4* row4 = (const float4*)(xc + (size_t)b * 1048576 + (size_t)p * 1024);
  float a0 = -3.4e38f, a1 = a0, a2 = a0;
  #pragma unroll
  for (int j = 0; j < 4; ++j){
    float4 v = row4[j * 64 + lane];
    ins3(a0, a1, a2, v.x); ins3(a0, a1, a2, v.y);
    ins3(a0, a1, a2, v.z); ins3(a0, a1, a2, v.w);
  }
  for (int off = 32; off; off >>= 1){
    float b0 = __shfl_xor(a0, off), b1 = __shfl_xor(a1, off), b2 = __shfl_xor(a2, off);
    ins3(a0, a1, a2, b0); ins3(a0, a1, a2, b1); ins3(a0, a1, a2, b2);
  }
  if (lane < 3){
    float v = (lane == 0) ? a0 : (lane == 1) ? a1 : a2;
    out[b * 3072 + lane * 1024 + p] = v;
  }
}

// ---------------- valq: top3 over p for each (b,q); 2-stage coalesced ----------------
__global__ __launch_bounds__(256) void topq1_k(float* __restrict__ ws){
  const float* xc = ws + XC_OFF;
  float* part = ws + PART_OFF;
  int bid = blockIdx.x;                       // 256: b(2) x pc(32) x qq(4)
  int qq = bid & 3, pc = (bid >> 2) & 31, b = bid >> 7;
  int q = qq * 256 + threadIdx.x;
  const float* base = xc + (size_t)b * 1048576 + q;
  float a0 = -3.4e38f, a1 = a0, a2 = a0;
  #pragma unroll 4
  for (int i = 0; i < 32; ++i) ins3(a0, a1, a2, base[(size_t)(pc * 32 + i) * 1024]);
  part[(size_t)((b * 32 + pc) * 3 + 0) * 1024 + q] = a0;
  part[(size_t)((b * 32 + pc) * 3 + 1) * 1024 + q] = a1;
  part[(size_t)((b * 32 + pc) * 3 + 2) * 1024 + q] = a2;
}

__global__ __launch_bounds__(256) void topq2_k(const float* __restrict__ ws, float* __restrict__ out){
  const float* part = ws + PART_OFF;
  int gid = blockIdx.x * 256 + threadIdx.x;   // 2048
  int b = gid >> 10, q = gid & 1023;
  float a0 = -3.4e38f, a1 = a0, a2 = a0;
  #pragma unroll 4
  for (int c = 0; c < 96; ++c) ins3(a0, a1, a2, part[(size_t)(b * 96 + c) * 1024 + q]);
  out[6144 + b * 3072 + q] = a0;
  out[6144 + b * 3072 + 1024 + q] = a1;
  out[6144 + b * 3072 + 2048 + q] = a2;
}

extern "C" void kernel_launch(void* const* d_in, const int* in_sizes, int n_in,
                              void* d_out, int out_size, void* d_ws, size_t ws_size,
                              hipStream_t stream){
  const float* xp = (const float*)d_in[0];
  const float* xq = (const float*)d_in[1];
  const float* W1 = (const float*)d_in[2];
  const float* B1 = (const float*)d_in[3];
  const float* W2 = (const float*)d_in[4];
  const float* B2 = (const float*)d_in[5];
  float* out = (float*)d_out;
  float* ws = (float*)d_ws;
  hipLaunchKernelGGL(norm_k,  dim3(256),  dim3(256), 0, stream, xp, xq, ws);
  hipLaunchKernelGGL(tab_k,   dim3(324),  dim3(256), 0, stream, W1, B1, W2, B2, ws);
  hipLaunchKernelGGL(gemm_k,  dim3(1024), dim3(256), 0, stream, xp, xq, ws);
  hipLaunchKernelGGL(conv_k,  dim3(1024), dim3(256), 0, stream, ws);
  hipLaunchKernelGGL(topp_k,  dim3(512),  dim3(256), 0, stream, ws, out);
  hipLaunchKernelGGL(topq1_k, dim3(256),  dim3(256), 0, stream, ws);
  hipLaunchKernelGGL(topq2_k, dim3(8),    dim3(256), 0, stream, ws, out);
}